// Round 4
// baseline (679.414 us; speedup 1.0000x reference)
//
#include <hip/hip_runtime.h>
#include <hip/hip_bf16.h>
#include <cstdint>
#include <cstddef>

// Problem constants (match reference)
#define B_TOT   2048
#define N_LIN   64
#define D_DIM   256
#define NSTEPS  4      // n_recurs + 1
#define BT      32     // batch rows per block (32 KB LDS -> 4 blocks/CU)

typedef __attribute__((ext_vector_type(8))) short short8;   // 8 bf16 = 4 VGPR
typedef __attribute__((ext_vector_type(4))) float f32x4;    // MFMA accumulator

// RNE split (prep kernel): fp32 -> bf16 hi + bf16 lo, both RNE.
__device__ __forceinline__ void split2(float f, unsigned short& h, unsigned short& l) {
    unsigned u = __float_as_uint(f);
    unsigned r = u + 0x7FFFu + ((u >> 16) & 1u);
    h = (unsigned short)(r >> 16);
    float hf = __uint_as_float(r & 0xFFFF0000u);
    float rem = f - hf;
    unsigned u2 = __float_as_uint(rem);
    unsigned r2 = u2 + 0x7FFFu + ((u2 >> 16) & 1u);
    l = (unsigned short)(r2 >> 16);
}

// Trunc-hi split (x path, hot loop): hi = truncate-to-bf16 (exact remainder),
// lo = RNE(f - hi).  ~7 VALU ops vs 10; combined repr error ~2^-16 rel.
__device__ __forceinline__ void split2t(float f, unsigned short& h, unsigned short& l) {
    unsigned u = __float_as_uint(f);
    h = (unsigned short)(u >> 16);
    float rem = f - __uint_as_float(u & 0xFFFF0000u);
    unsigned u2 = __float_as_uint(rem);
    unsigned r2 = u2 + 0x7FFFu + ((u2 >> 16) & 1u);
    l = (unsigned short)(r2 >> 16);
}

__device__ __forceinline__ float bf16_to_f(unsigned short s) {
    return __uint_as_float((unsigned)s << 16);
}

// ---------------------------------------------------------------------------
// Prep (fast path only): masked weights -> bf16 hi/lo split arrays in d_ws.
// ---------------------------------------------------------------------------
__global__ void prep_kernel(const float* __restrict__ w, const float* __restrict__ wm,
                            unsigned short* __restrict__ w_hi,
                            unsigned short* __restrict__ w_lo) {
    const int nW4 = N_LIN * D_DIM * D_DIM / 4;   // 1,048,576 float4 groups
    int stride = gridDim.x * blockDim.x;
    for (int i = blockIdx.x * blockDim.x + threadIdx.x; i < nW4; i += stride) {
        float4 wv = ((const float4*)w)[i];
        float4 mv = ((const float4*)wm)[i];
        ushort4 h, l;
        split2(wv.x * mv.x, h.x, l.x);
        split2(wv.y * mv.y, h.y, l.y);
        split2(wv.z * mv.z, h.z, l.z);
        split2(wv.w * mv.w, h.w, l.w);
        ((ushort4*)w_hi)[i] = h;
        ((ushort4*)w_lo)[i] = l;
    }
}

// ---------------------------------------------------------------------------
// Fused 4-step recurrence.  One block = 32 batch rows x one linear n.
// 512 threads / 8 waves; x in LDS as bf16 hi/lo (swizzled, 32 KB) serves only
// the MFMA B-fragments; the fp32 residual stream lives in REGISTERS.
//
// v-next vs round 3:
//  * BT 64->32: LDS 64->32 KB => 4 blocks/CU = 32 waves/CU = 8 waves/SIMD
//    (occupancy granularity: 8 waves/SIMD requires <=64 VGPR, which the
//    compiler picks anyway).  Grid 2048->4096.
//  * Register-resident residual xr[2][2][4]: with BT=32 each wave covers ALL
//    batch rows, so each lane updates the same (r,c) cells every step ->
//    epilogue needs NO LDS read-back / reconstruct; final store from regs.
//  * Bias folded into acc init via 1 KB LDS table (frees 8 VGPR).
//  * Trunc-hi split in the hot path (30% fewer VALU ops).
//  * No explicit w double-buffer (VGPR budget); 8 waves/SIMD do the hiding.
// ---------------------------------------------------------------------------
template <bool ONFLY>
__global__ __launch_bounds__(512, 8)
void fused_kernel(const float* __restrict__ xin,
                  const unsigned short* __restrict__ w_hi,
                  const unsigned short* __restrict__ w_lo,
                  const float* __restrict__ wraw,
                  const float* __restrict__ wmask,
                  const float* __restrict__ braw,
                  const float* __restrict__ bmask,
                  float* __restrict__ xout) {
    __shared__ unsigned short xh[BT * 256];   // 16 KB
    __shared__ unsigned short xl[BT * 256];   // 16 KB
    __shared__ float s_bias[D_DIM];           // 1 KB (masked bias)
    __shared__ int s_cnt[4];

    const int tid  = threadIdx.x;
    const int lane = tid & 63;
    const int wvid = tid >> 6;      // 0..7: owns j-tiles {wvid, wvid+8}
    const int quad = lane >> 4;
    const int l16  = lane & 15;

    // XCD-aware swizzle: all 64 batch-tiles of a given n share blockIdx%8,
    // so each XCD's L2 only holds 8 n's worth of weights (2 MB < 4 MB).
    const int xcd = blockIdx.x & 7;
    const int j8  = blockIdx.x >> 3;         // 0..511
    const int n   = (xcd << 3) | (j8 & 7);   // 0..63
    const int btk = j8 >> 3;                 // 0..63

    const size_t row_stride = (size_t)N_LIN * D_DIM;  // 16384 floats between batch rows
    const float* xsrc = xin  + ((size_t)btk * BT * N_LIN + n) * D_DIM;
    float*       xdst = xout + ((size_t)btk * BT * N_LIN + n) * D_DIM;

    // ---- initial load: global fp32 -> LDS bf16 hi/lo (coalesced float4) ----
    for (int i = tid; i < BT * (D_DIM / 4); i += 512) {
        int r = i >> 6, c4 = i & 63;
        float4 v = ((const float4*)(xsrc + (size_t)r * row_stride))[c4];
        ushort4 h, l;
        split2t(v.x, h.x, l.x);
        split2t(v.y, h.y, l.y);
        split2t(v.z, h.z, l.z);
        split2t(v.w, h.w, l.w);
        int pi = r * 256 + ((((c4 >> 1) ^ (r & 7))) << 3) + ((c4 & 1) << 2);
        *((ushort4*)&xh[pi]) = h;
        *((ushort4*)&xl[pi]) = l;
    }

    // ---- masked bias table (1 KB LDS) ----
    if (tid < D_DIM) s_bias[tid] = braw[n * D_DIM + tid] * bmask[n * D_DIM + tid];

    // ---- runtime n_act from bias_mask (prefix-active structure) ----
    if (wvid < 4) {
        float bv = bmask[n * D_DIM + wvid * 64 + lane];
        unsigned long long actm = __ballot(bv != 0.0f);
        if (lane == 0) s_cnt[wvid] = __popcll(actm);
    }

    float bmj[2];   // ONFLY: w-row (j) mask scalar per owned j-tile
    if (ONFLY) {
        #pragma unroll
        for (int u = 0; u < 2; ++u)
            bmj[u] = bmask[n * D_DIM + (wvid + 8 * u) * 16 + l16];
    }

    // w-fragment base: lane covers w[j = (wvid+8u)*16 + l16][i = kt*32 + quad*8 .. +7]
    const size_t wbase = ((size_t)n * D_DIM + (size_t)wvid * 16 + l16) * D_DIM + (size_t)quad * 8;
    const size_t ustride = (size_t)128 * D_DIM;   // 8 j-tiles * 16 rows

    __syncthreads();

    const int n_act  = s_cnt[0] + s_cnt[1] + s_cnt[2] + s_cnt[3];   // {128..256}, mult of 32
    const int kt_lim = n_act >> 5;                                   // active k-tiles (4..8)
    const int njt    = n_act >> 4;                                   // active j-tiles (8..16)
    const bool u1a   = (wvid + 8) < njt;                             // second tile active?

    // ---- fp32 residual in registers: xr[u][bt][rg] for cell
    //      (r = bt*16 + l16, c = (wvid+8u)*16 + quad*4 + rg).
    //      Init by reconstructing from LDS (same repr error as before). ----
    float xr[2][2][4];
    #pragma unroll
    for (int u = 0; u < 2; ++u)
        #pragma unroll
        for (int bt = 0; bt < 2; ++bt) {
            int r  = bt * 16 + l16;
            int c0 = (wvid + 8 * u) * 16 + quad * 4;
            int pi = r * 256 + ((((c0 >> 3) ^ (r & 7))) << 3) + (c0 & 7);
            ushort4 oh = *((const ushort4*)&xh[pi]);
            ushort4 ol = *((const ushort4*)&xl[pi]);
            xr[u][bt][0] = bf16_to_f(oh.x) + bf16_to_f(ol.x);
            xr[u][bt][1] = bf16_to_f(oh.y) + bf16_to_f(ol.y);
            xr[u][bt][2] = bf16_to_f(oh.z) + bf16_to_f(ol.z);
            xr[u][bt][3] = bf16_to_f(oh.w) + bf16_to_f(ol.w);
        }

    #pragma unroll 1
    for (int step = 0; step < NSTEPS; ++step) {
        // acc init = masked bias (zero for inactive j, so inactive u adds 0)
        f32x4 acc[2][2];
        {
            f32x4 bv0 = *((const f32x4*)&s_bias[wvid * 16 + quad * 4]);
            f32x4 bv1 = *((const f32x4*)&s_bias[wvid * 16 + 128 + quad * 4]);
            acc[0][0] = bv0; acc[0][1] = bv0;
            acc[1][0] = bv1; acc[1][1] = bv1;
        }

        #pragma unroll 2
        for (int kt = 0; kt < kt_lim; ++kt) {
            // ---- w fragments (A operand) ----
            short8 wh0, wl0, wh1, wl1;
            if (!ONFLY) {
                size_t off = wbase + (size_t)(kt << 5);
                wh0 = *((const short8*)(w_hi + off));
                wl0 = *((const short8*)(w_lo + off));
                if (u1a) {
                    wh1 = *((const short8*)(w_hi + off + ustride));
                    wl1 = *((const short8*)(w_lo + off + ustride));
                }
            } else {
                const float* bmi_p = bmask + n * D_DIM + kt * 32 + quad * 8;
                float4 mi0 = ((const float4*)bmi_p)[0];
                float4 mi1 = ((const float4*)bmi_p)[1];
                float mi[8] = {mi0.x, mi0.y, mi0.z, mi0.w, mi1.x, mi1.y, mi1.z, mi1.w};
                #pragma unroll
                for (int u = 0; u < 2; ++u) {
                    if (u == 1 && !u1a) break;
                    const float* wp = wraw + wbase + (size_t)u * ustride + (size_t)(kt << 5);
                    float4 w0 = ((const float4*)wp)[0];
                    float4 w1 = ((const float4*)wp)[1];
                    float wvv[8] = {w0.x, w0.y, w0.z, w0.w, w1.x, w1.y, w1.z, w1.w};
                    short8 th, tl;
                    #pragma unroll
                    for (int j = 0; j < 8; ++j) {
                        unsigned short h, l;
                        split2t(wvv[j] * bmj[u] * mi[j], h, l);
                        th[j] = (short)h;
                        tl[j] = (short)l;
                    }
                    if (u == 0) { wh0 = th; wl0 = tl; }
                    else        { wh1 = th; wl1 = tl; }
                }
            }
            // ---- x fragments (B operand; LDS, swizzled) + MFMA ----
            const int c0 = kt * 32 + quad * 8;
            #pragma unroll
            for (int bt = 0; bt < 2; ++bt) {
                int m  = bt * 16 + l16;
                int pi = m * 256 + ((((c0 >> 3) ^ (m & 7))) << 3);
                short8 x8h = *((const short8*)&xh[pi]);
                short8 x8l = *((const short8*)&xl[pi]);
                acc[0][bt] = __builtin_amdgcn_mfma_f32_16x16x32_bf16(wh0, x8h, acc[0][bt], 0, 0, 0);
                acc[0][bt] = __builtin_amdgcn_mfma_f32_16x16x32_bf16(wh0, x8l, acc[0][bt], 0, 0, 0);
                acc[0][bt] = __builtin_amdgcn_mfma_f32_16x16x32_bf16(wl0, x8h, acc[0][bt], 0, 0, 0);
                if (u1a) {
                    acc[1][bt] = __builtin_amdgcn_mfma_f32_16x16x32_bf16(wh1, x8h, acc[1][bt], 0, 0, 0);
                    acc[1][bt] = __builtin_amdgcn_mfma_f32_16x16x32_bf16(wh1, x8l, acc[1][bt], 0, 0, 0);
                    acc[1][bt] = __builtin_amdgcn_mfma_f32_16x16x32_bf16(wl1, x8h, acc[1][bt], 0, 0, 0);
                }
            }
        }

        __syncthreads();   // all waves' x-reads done before x is overwritten

        const bool last = (step == NSTEPS - 1);
        #pragma unroll
        for (int u = 0; u < 2; ++u) {
            const bool act = (u == 0) || u1a;
            #pragma unroll
            for (int bt = 0; bt < 2; ++bt) {
                int r  = bt * 16 + l16;
                int c0 = (wvid + 8 * u) * 16 + quad * 4;
                // acc holds bias-seeded result; inactive u has acc == 0 (masked
                // bias) and no MFMA contributions, so the update is a no-op.
                #pragma unroll
                for (int rg = 0; rg < 4; ++rg)
                    xr[u][bt][rg] += fmaxf(acc[u][bt][rg], 0.f);
                if (last) {
                    float4 o;
                    o.x = xr[u][bt][0]; o.y = xr[u][bt][1];
                    o.z = xr[u][bt][2]; o.w = xr[u][bt][3];
                    *((float4*)(xdst + (size_t)r * row_stride + c0)) = o;  // dwordx4
                } else if (act) {
                    int pi = r * 256 + ((((c0 >> 3) ^ (r & 7))) << 3) + (c0 & 7);
                    ushort4 h, l;
                    split2t(xr[u][bt][0], h.x, l.x);
                    split2t(xr[u][bt][1], h.y, l.y);
                    split2t(xr[u][bt][2], h.z, l.z);
                    split2t(xr[u][bt][3], h.w, l.w);
                    *((ushort4*)&xh[pi]) = h;                 // ds_write_b64
                    *((ushort4*)&xl[pi]) = l;
                }
            }
        }
        if (!last) __syncthreads();   // new x fully written before next step
    }
}

// ---------------------------------------------------------------------------
extern "C" void kernel_launch(void* const* d_in, const int* in_sizes, int n_in,
                              void* d_out, int out_size, void* d_ws, size_t ws_size,
                              hipStream_t stream) {
    const float* x  = (const float*)d_in[0];
    const float* w  = (const float*)d_in[1];
    const float* b  = (const float*)d_in[2];
    const float* wm = (const float*)d_in[3];
    const float* bm = (const float*)d_in[4];
    float* out = (float*)d_out;

    const size_t needW = (size_t)2 * N_LIN * D_DIM * D_DIM * sizeof(unsigned short); // 16 MB
    const int grid = (B_TOT / BT) * N_LIN;   // 4096 blocks

    if (ws_size >= needW) {
        // Fast path: pre-split masked weights into workspace once per call.
        unsigned short* w_hi = (unsigned short*)d_ws;
        unsigned short* w_lo = w_hi + (size_t)N_LIN * D_DIM * D_DIM;
        prep_kernel<<<1024, 256, 0, stream>>>(w, wm, w_hi, w_lo);
        fused_kernel<false><<<grid, 512, 0, stream>>>(x, w_hi, w_lo, w, wm, b, bm, out);
    } else {
        // Fallback: no scratch — mask+split W on the fly inside the kernel.
        fused_kernel<true><<<grid, 512, 0, stream>>>(x, nullptr, nullptr, w, wm, b, bm, out);
    }
}

// Round 6
// 651.224 us; speedup vs baseline: 1.0433x; 1.0433x over previous
//
#include <hip/hip_runtime.h>
#include <hip/hip_bf16.h>
#include <cstdint>
#include <cstddef>

// Problem constants (match reference)
#define B_TOT   2048
#define N_LIN   64
#define D_DIM   256
#define NSTEPS  4      // n_recurs + 1
#define BT      32     // batch rows per block (32 KB LDS for x hi/lo)

typedef __attribute__((ext_vector_type(8))) short short8;   // 8 bf16 = 4 VGPR
typedef __attribute__((ext_vector_type(4))) float f32x4;    // MFMA accumulator

// RNE split (prep kernel): fp32 -> bf16 hi + bf16 lo, both RNE.
__device__ __forceinline__ void split2(float f, unsigned short& h, unsigned short& l) {
    unsigned u = __float_as_uint(f);
    unsigned r = u + 0x7FFFu + ((u >> 16) & 1u);
    h = (unsigned short)(r >> 16);
    float hf = __uint_as_float(r & 0xFFFF0000u);
    float rem = f - hf;
    unsigned u2 = __float_as_uint(rem);
    unsigned r2 = u2 + 0x7FFFu + ((u2 >> 16) & 1u);
    l = (unsigned short)(r2 >> 16);
}

// Trunc-hi split (x path, hot loop): hi = truncate-to-bf16 (exact remainder),
// lo = RNE(f - hi).  Fewer VALU ops; combined repr error ~2^-16 rel.
__device__ __forceinline__ void split2t(float f, unsigned short& h, unsigned short& l) {
    unsigned u = __float_as_uint(f);
    h = (unsigned short)(u >> 16);
    float rem = f - __uint_as_float(u & 0xFFFF0000u);
    unsigned u2 = __float_as_uint(rem);
    unsigned r2 = u2 + 0x7FFFu + ((u2 >> 16) & 1u);
    l = (unsigned short)(r2 >> 16);
}

__device__ __forceinline__ float bf16_to_f(unsigned short s) {
    return __uint_as_float((unsigned)s << 16);
}

// ---------------------------------------------------------------------------
// Prep (fast path only): masked weights -> bf16 hi/lo split arrays in d_ws.
// ---------------------------------------------------------------------------
__global__ void prep_kernel(const float* __restrict__ w, const float* __restrict__ wm,
                            unsigned short* __restrict__ w_hi,
                            unsigned short* __restrict__ w_lo) {
    const int nW4 = N_LIN * D_DIM * D_DIM / 4;   // 1,048,576 float4 groups
    int stride = gridDim.x * blockDim.x;
    for (int i = blockIdx.x * blockDim.x + threadIdx.x; i < nW4; i += stride) {
        float4 wv = ((const float4*)w)[i];
        float4 mv = ((const float4*)wm)[i];
        ushort4 h, l;
        split2(wv.x * mv.x, h.x, l.x);
        split2(wv.y * mv.y, h.y, l.y);
        split2(wv.z * mv.z, h.z, l.z);
        split2(wv.w * mv.w, h.w, l.w);
        ((ushort4*)w_hi)[i] = h;
        ((ushort4*)w_lo)[i] = l;
    }
}

// ---------------------------------------------------------------------------
// Fused 4-step recurrence.  One block = 32 batch rows x one linear n.
// 512 threads / 8 waves.  x for MFMA consumption lives in LDS as bf16 hi/lo
// (swizzled, 32 KB); the fp32 residual stream lives in REGISTERS (xr),
// loaded once from global fp32 (exact) and stored fp32 at the end.
//
// v-next vs round 5: REVERT math to the proven bf16 hi/lo 3-MFMA scheme
// (validated 5x, absmax 0.0625 vs threshold 0.3275); the fp16 single-MFMA
// experiment produced absmax 1.3e6 (a real bug, not precision — cause not
// identified by inspection, so the risky path is abandoned).
// vs round 4: __launch_bounds__(512,4) instead of (512,8) — round 4's
// forced <=64 VGPR spilled the ~76-reg working set to scratch
// (VGPR_Count=32, WRITE 245 MB).  With 128 available the set fits honestly.
// xr is initialized from GLOBAL (exact fp32; also fixes round 4's latent
// unbarriered-LDS-read race).
// ---------------------------------------------------------------------------
template <bool ONFLY>
__global__ __launch_bounds__(512, 4)
void fused_kernel(const float* __restrict__ xin,
                  const unsigned short* __restrict__ w_hi,
                  const unsigned short* __restrict__ w_lo,
                  const float* __restrict__ wraw,
                  const float* __restrict__ braw,
                  const float* __restrict__ bmask,
                  float* __restrict__ xout) {
    __shared__ unsigned short xh[BT * 256];   // 16 KB
    __shared__ unsigned short xl[BT * 256];   // 16 KB
    __shared__ float s_bias[D_DIM];           // 1 KB (masked bias)
    __shared__ int s_cnt[4];

    const int tid  = threadIdx.x;
    const int lane = tid & 63;
    const int wvid = tid >> 6;      // 0..7: owns j-tiles {wvid, wvid+8}
    const int quad = lane >> 4;
    const int l16  = lane & 15;

    // XCD-aware swizzle: all 64 batch-tiles of a given n share blockIdx%8.
    const int xcd = blockIdx.x & 7;
    const int j8  = blockIdx.x >> 3;         // 0..511
    const int n   = (xcd << 3) | (j8 & 7);   // 0..63
    const int btk = j8 >> 3;                 // 0..63

    const size_t row_stride = (size_t)N_LIN * D_DIM;  // 16384 floats between batch rows
    const float* xsrc = xin  + ((size_t)btk * BT * N_LIN + n) * D_DIM;
    float*       xdst = xout + ((size_t)btk * BT * N_LIN + n) * D_DIM;

    // ---- initial load: global fp32 -> LDS bf16 hi/lo (coalesced float4) ----
    for (int i = tid; i < BT * (D_DIM / 4); i += 512) {
        int r = i >> 6, c4 = i & 63;
        float4 v = ((const float4*)(xsrc + (size_t)r * row_stride))[c4];
        ushort4 h, l;
        split2t(v.x, h.x, l.x);
        split2t(v.y, h.y, l.y);
        split2t(v.z, h.z, l.z);
        split2t(v.w, h.w, l.w);
        int pi = r * 256 + ((((c4 >> 1) ^ (r & 7))) << 3) + ((c4 & 1) << 2);
        *((ushort4*)&xh[pi]) = h;
        *((ushort4*)&xl[pi]) = l;
    }

    // ---- masked bias table (1 KB LDS) ----
    if (tid < D_DIM) s_bias[tid] = braw[n * D_DIM + tid] * bmask[n * D_DIM + tid];

    // ---- runtime n_act from bias_mask (prefix-active structure) ----
    if (wvid < 4) {
        float bv = bmask[n * D_DIM + wvid * 64 + lane];
        unsigned long long actm = __ballot(bv != 0.0f);
        if (lane == 0) s_cnt[wvid] = __popcll(actm);
    }

    float bmj[2];   // ONFLY: w-row (j) mask scalar per owned j-tile
    if (ONFLY) {
        #pragma unroll
        for (int u = 0; u < 2; ++u)
            bmj[u] = bmask[n * D_DIM + (wvid + 8 * u) * 16 + l16];
    }

    // w-fragment base: lane covers w[j = (wvid+8u)*16 + l16][i = kt*32 + quad*8 .. +7]
    const size_t wbase = ((size_t)n * D_DIM + (size_t)wvid * 16 + l16) * D_DIM + (size_t)quad * 8;
    const size_t ustride = (size_t)128 * D_DIM;   // 8 j-tiles * 16 rows

    // ---- fp32 residual in registers, loaded EXACTLY from global fp32.
    //      Cell (r = bt*16 + l16, c = (wvid+8u)*16 + quad*4 + rg). ----
    float xr[2][2][4];
    #pragma unroll
    for (int u = 0; u < 2; ++u)
        #pragma unroll
        for (int bt = 0; bt < 2; ++bt) {
            int r  = bt * 16 + l16;
            int c0 = (wvid + 8 * u) * 16 + quad * 4;
            float4 v = *((const float4*)(xsrc + (size_t)r * row_stride + c0));
            xr[u][bt][0] = v.x; xr[u][bt][1] = v.y;
            xr[u][bt][2] = v.z; xr[u][bt][3] = v.w;
        }

    __syncthreads();

    const int n_act  = s_cnt[0] + s_cnt[1] + s_cnt[2] + s_cnt[3];   // {128..256}, mult of 32
    const int kt_lim = n_act >> 5;                                   // active k-tiles (4..8)
    const int njt    = n_act >> 4;                                   // active j-tiles (8..16)
    const bool u1a   = (wvid + 8) < njt;                             // second tile active?

    #pragma unroll 1
    for (int step = 0; step < NSTEPS; ++step) {
        // acc init = masked bias (zero for inactive j -> relu(0) -> no-op)
        f32x4 acc[2][2];
        {
            f32x4 bv0 = *((const f32x4*)&s_bias[wvid * 16 + quad * 4]);
            f32x4 bv1 = *((const f32x4*)&s_bias[wvid * 16 + 128 + quad * 4]);
            acc[0][0] = bv0; acc[0][1] = bv0;
            acc[1][0] = bv1; acc[1][1] = bv1;
        }

        #pragma unroll 2
        for (int kt = 0; kt < kt_lim; ++kt) {
            // ---- w fragments (A operand, bf16 hi/lo) ----
            short8 wh0, wl0, wh1, wl1;
            if (!ONFLY) {
                size_t off = wbase + (size_t)(kt << 5);
                wh0 = *((const short8*)(w_hi + off));
                wl0 = *((const short8*)(w_lo + off));
                if (u1a) {
                    wh1 = *((const short8*)(w_hi + off + ustride));
                    wl1 = *((const short8*)(w_lo + off + ustride));
                }
            } else {
                const float* bmi_p = bmask + n * D_DIM + kt * 32 + quad * 8;
                float4 mi0 = ((const float4*)bmi_p)[0];
                float4 mi1 = ((const float4*)bmi_p)[1];
                float mi[8] = {mi0.x, mi0.y, mi0.z, mi0.w, mi1.x, mi1.y, mi1.z, mi1.w};
                #pragma unroll
                for (int u = 0; u < 2; ++u) {
                    if (u == 1 && !u1a) break;
                    const float* wp = wraw + wbase + (size_t)u * ustride + (size_t)(kt << 5);
                    float4 a0 = ((const float4*)wp)[0];
                    float4 a1 = ((const float4*)wp)[1];
                    float wvv[8] = {a0.x, a0.y, a0.z, a0.w, a1.x, a1.y, a1.z, a1.w};
                    short8 th, tl;
                    #pragma unroll
                    for (int j = 0; j < 8; ++j) {
                        unsigned short h, l;
                        split2t(wvv[j] * bmj[u] * mi[j], h, l);
                        th[j] = (short)h;
                        tl[j] = (short)l;
                    }
                    if (u == 0) { wh0 = th; wl0 = tl; }
                    else        { wh1 = th; wl1 = tl; }
                }
            }
            // ---- x fragments (B operand; LDS, swizzled) + 3-product MFMA ----
            const int c0 = kt * 32 + quad * 8;
            #pragma unroll
            for (int bt = 0; bt < 2; ++bt) {
                int m  = bt * 16 + l16;
                int pi = m * 256 + ((((c0 >> 3) ^ (m & 7))) << 3);
                short8 x8h = *((const short8*)&xh[pi]);
                short8 x8l = *((const short8*)&xl[pi]);
                acc[0][bt] = __builtin_amdgcn_mfma_f32_16x16x32_bf16(wh0, x8h, acc[0][bt], 0, 0, 0);
                acc[0][bt] = __builtin_amdgcn_mfma_f32_16x16x32_bf16(wh0, x8l, acc[0][bt], 0, 0, 0);
                acc[0][bt] = __builtin_amdgcn_mfma_f32_16x16x32_bf16(wl0, x8h, acc[0][bt], 0, 0, 0);
                if (u1a) {
                    acc[1][bt] = __builtin_amdgcn_mfma_f32_16x16x32_bf16(wh1, x8h, acc[1][bt], 0, 0, 0);
                    acc[1][bt] = __builtin_amdgcn_mfma_f32_16x16x32_bf16(wh1, x8l, acc[1][bt], 0, 0, 0);
                    acc[1][bt] = __builtin_amdgcn_mfma_f32_16x16x32_bf16(wl1, x8h, acc[1][bt], 0, 0, 0);
                }
            }
        }

        __syncthreads();   // all waves' x-reads done before x is overwritten

        const bool last = (step == NSTEPS - 1);
        #pragma unroll
        for (int u = 0; u < 2; ++u) {
            const bool act = (u == 0) || u1a;
            #pragma unroll
            for (int bt = 0; bt < 2; ++bt) {
                int r  = bt * 16 + l16;
                int c0 = (wvid + 8 * u) * 16 + quad * 4;
                // inactive u: acc == 0 (masked bias, no MFMA) -> relu(0) -> no-op
                #pragma unroll
                for (int rg = 0; rg < 4; ++rg)
                    xr[u][bt][rg] += fmaxf(acc[u][bt][rg], 0.f);
                if (last) {
                    float4 o;
                    o.x = xr[u][bt][0]; o.y = xr[u][bt][1];
                    o.z = xr[u][bt][2]; o.w = xr[u][bt][3];
                    *((float4*)(xdst + (size_t)r * row_stride + c0)) = o;  // dwordx4
                } else if (act) {
                    int pi = r * 256 + ((((c0 >> 3) ^ (r & 7))) << 3) + (c0 & 7);
                    ushort4 h, l;
                    split2t(xr[u][bt][0], h.x, l.x);
                    split2t(xr[u][bt][1], h.y, l.y);
                    split2t(xr[u][bt][2], h.z, l.z);
                    split2t(xr[u][bt][3], h.w, l.w);
                    *((ushort4*)&xh[pi]) = h;                 // ds_write_b64
                    *((ushort4*)&xl[pi]) = l;
                }
            }
        }
        if (!last) __syncthreads();   // new x fully written before next step
    }
}

// ---------------------------------------------------------------------------
extern "C" void kernel_launch(void* const* d_in, const int* in_sizes, int n_in,
                              void* d_out, int out_size, void* d_ws, size_t ws_size,
                              hipStream_t stream) {
    const float* x  = (const float*)d_in[0];
    const float* w  = (const float*)d_in[1];
    const float* b  = (const float*)d_in[2];
    const float* wm = (const float*)d_in[3];
    const float* bm = (const float*)d_in[4];
    float* out = (float*)d_out;

    const size_t needW = (size_t)2 * N_LIN * D_DIM * D_DIM * sizeof(unsigned short); // 16 MB
    const int grid = (B_TOT / BT) * N_LIN;   // 4096 blocks

    if (ws_size >= needW) {
        // Fast path: pre-split masked weights into workspace once per call.
        unsigned short* w_hi = (unsigned short*)d_ws;
        unsigned short* w_lo = w_hi + (size_t)N_LIN * D_DIM * D_DIM;
        prep_kernel<<<1024, 256, 0, stream>>>(w, wm, w_hi, w_lo);
        fused_kernel<false><<<grid, 512, 0, stream>>>(x, w_hi, w_lo, w, b, bm, out);
    } else {
        // Fallback: no scratch — mask+split W on the fly inside the kernel.
        fused_kernel<true><<<grid, 512, 0, stream>>>(x, nullptr, nullptr, w, b, bm, out);
    }
}